// Round 1
// baseline (661.605 us; speedup 1.0000x reference)
//
#include <hip/hip_runtime.h>
#include <hip/hip_bf16.h>
#include <math.h>

typedef __attribute__((ext_vector_type(8))) short short8;
typedef __attribute__((ext_vector_type(4))) float f32x4;

#define MFMA_BF16 __builtin_amdgcn_mfma_f32_16x16x32_bf16

static constexpr int Dm = 1024;   // model dim
static constexpr int Tm = 2048;   // seq len
static constexpr int Bb = 4;      // batch
static constexpr int NHm = 16;    // heads
static constexpr int HDm = 64;    // head dim
static constexpr int Mtot = Bb * Tm;  // 8192 rows

__device__ __forceinline__ unsigned short f2bf(float f) {
  unsigned int u = __float_as_uint(f);
  u += 0x7FFFu + ((u >> 16) & 1u);  // RNE
  return (unsigned short)(u >> 16);
}

__global__ __launch_bounds__(256) void cvt_kernel(const float* __restrict__ src,
                                                  short* __restrict__ dst, int n) {
  int stride = gridDim.x * blockDim.x;
  for (int i = blockIdx.x * blockDim.x + threadIdx.x; i * 4 < n; i += stride) {
    float4 v = reinterpret_cast<const float4*>(src)[i];
    short4 o;
    o.x = (short)f2bf(v.x);
    o.y = (short)f2bf(v.y);
    o.z = (short)f2bf(v.z);
    o.w = (short)f2bf(v.w);
    reinterpret_cast<short4*>(dst)[i] = o;
  }
}

// C = A(M x 1024, bf16 row-major) @ W(1024 x 1024, bf16 row-major K x N)
// MODE 0: write bf16 scattered to (B,H,T,hd) head layout
// MODE 1: write fp32 to C row-major with fp32 bias
template <int MODE>
__global__ __launch_bounds__(256) void gemm128_kernel(
    const short* __restrict__ Ags, const short* __restrict__ Wgs,
    short* __restrict__ Cbf, float* __restrict__ Cf, const float* __restrict__ bias) {
  constexpr int PITCH = 40;  // 32 + 8 pad (keeps 16B alignment, breaks bank stride)
  __shared__ __align__(16) short Asl[128 * PITCH];
  __shared__ __align__(16) short Btl[128 * PITCH];  // [n][k] transposed tile
  const int tid = threadIdx.x;
  const int lane = tid & 63;
  const int w = tid >> 6;
  const int wr = (w >> 1) * 64, wc = (w & 1) * 64;
  const int g = lane >> 4;
  const int lr = lane & 15;
  const int m0 = blockIdx.y * 128;
  const int n0 = blockIdx.x * 128;

  f32x4 acc[4][4];
#pragma unroll
  for (int mi = 0; mi < 4; ++mi)
#pragma unroll
    for (int ni = 0; ni < 4; ++ni)
#pragma unroll
      for (int r = 0; r < 4; ++r) acc[mi][ni][r] = 0.f;

  for (int kt = 0; kt < Dm / 32; ++kt) {
    __syncthreads();
#pragma unroll
    for (int p = 0; p < 2; ++p) {
      int idx = tid + p * 256;
      // A tile: 128 rows x 32 cols
      int r = idx >> 2, c8 = (idx & 3) * 8;
      short8 av = *reinterpret_cast<const short8*>(Ags + (size_t)(m0 + r) * Dm + kt * 32 + c8);
      *reinterpret_cast<short8*>(&Asl[r * PITCH + c8]) = av;
      // B tile: 32 k-rows x 128 n-cols, transposed into Btl[n][k]
      int kr = idx >> 4, nc8 = (idx & 15) * 8;
      short8 wv = *reinterpret_cast<const short8*>(Wgs + (size_t)(kt * 32 + kr) * Dm + n0 + nc8);
#pragma unroll
      for (int i = 0; i < 8; ++i) Btl[(nc8 + i) * PITCH + kr] = wv[i];
    }
    __syncthreads();
    short8 a[4], b[4];
#pragma unroll
    for (int mi = 0; mi < 4; ++mi)
      a[mi] = *reinterpret_cast<const short8*>(&Asl[(wr + mi * 16 + lr) * PITCH + g * 8]);
#pragma unroll
    for (int ni = 0; ni < 4; ++ni)
      b[ni] = *reinterpret_cast<const short8*>(&Btl[(wc + ni * 16 + lr) * PITCH + g * 8]);
#pragma unroll
    for (int mi = 0; mi < 4; ++mi)
#pragma unroll
      for (int ni = 0; ni < 4; ++ni)
        acc[mi][ni] = MFMA_BF16(a[mi], b[ni], acc[mi][ni], 0, 0, 0);
  }

#pragma unroll
  for (int mi = 0; mi < 4; ++mi)
#pragma unroll
    for (int ni = 0; ni < 4; ++ni)
#pragma unroll
      for (int r = 0; r < 4; ++r) {
        int mg = m0 + wr + mi * 16 + g * 4 + r;  // C/D: row=(lane>>4)*4+reg
        int ng = n0 + wc + ni * 16 + lr;         // C/D: col=lane&15
        float v = acc[mi][ni][r];
        if (MODE == 0) {
          int b_ = mg >> 11, t_ = mg & 2047, h_ = ng >> 6, d_ = ng & 63;
          Cbf[(((size_t)(b_ * NHm + h_) * Tm) + t_) * HDm + d_] = (short)f2bf(v);
        } else {
          Cf[(size_t)mg * Dm + ng] = v + bias[ng];
        }
      }
}

// Flash attention, causal. One block = one (b,h) and 64 queries; 4 waves x 16 q.
__global__ __launch_bounds__(256) void attn_kernel(
    const short* __restrict__ Qg, const short* __restrict__ Kg,
    const short* __restrict__ Vg, short* __restrict__ Og) {
  constexpr int KP = 72;  // 64 + 8 pad
  __shared__ __align__(16) short Kl[64 * KP];      // [key][d]
  __shared__ __align__(16) short Vt[64 * KP];      // [d][key]
  __shared__ __align__(16) short Pl[4][16 * KP];   // per-wave [q][key]
  const int tid = threadIdx.x;
  const int lane = tid & 63;
  const int w = tid >> 6;
  const int g = lane >> 4;
  const int lr = lane & 15;
  const int bh = blockIdx.y;
  const int q0 = blockIdx.x * 64;
  const short* Qs = Qg + ((size_t)bh * Tm + q0) * HDm;
  const short* Ks = Kg + (size_t)bh * Tm * HDm;
  const short* Vs = Vg + (size_t)bh * Tm * HDm;

  // Q fragments held in registers: A[row=lr][k = kk*32 + g*8 + j]
  short8 qf[2];
  qf[0] = *reinterpret_cast<const short8*>(Qs + (w * 16 + lr) * HDm + g * 8);
  qf[1] = *reinterpret_cast<const short8*>(Qs + (w * 16 + lr) * HDm + 32 + g * 8);

  f32x4 o[4];
  float m_i[4], l_i[4];
#pragma unroll
  for (int r = 0; r < 4; ++r) {
    m_i[r] = -1e30f;
    l_i[r] = 0.f;
#pragma unroll
    for (int di = 0; di < 4; ++di) o[di][r] = 0.f;
  }

  const int nt = q0 / 64 + 1;
  for (int t = 0; t < nt; ++t) {
    const int k0 = t * 64;
    __syncthreads();
    // stage K [key][d] and V transposed [d][key]
#pragma unroll
    for (int p = 0; p < 2; ++p) {
      int idx = tid + p * 256;
      int kr = idx >> 3, c8 = (idx & 7) * 8;
      short8 kv = *reinterpret_cast<const short8*>(Ks + (size_t)(k0 + kr) * HDm + c8);
      *reinterpret_cast<short8*>(&Kl[kr * KP + c8]) = kv;
      short8 vv = *reinterpret_cast<const short8*>(Vs + (size_t)(k0 + kr) * HDm + c8);
#pragma unroll
      for (int i = 0; i < 8; ++i) Vt[(c8 + i) * KP + kr] = vv[i];
    }
    __syncthreads();

    // S = Q K^T for 4 key sub-tiles of 16
    f32x4 s[4];
#pragma unroll
    for (int ni = 0; ni < 4; ++ni) {
      f32x4 acc;
#pragma unroll
      for (int r = 0; r < 4; ++r) acc[r] = 0.f;
#pragma unroll
      for (int kk = 0; kk < 2; ++kk) {
        short8 kf = *reinterpret_cast<const short8*>(&Kl[(ni * 16 + lr) * KP + kk * 32 + g * 8]);
        acc = MFMA_BF16(qf[kk], kf, acc, 0, 0, 0);
      }
      s[ni] = acc;
    }

    const bool diag = (t == nt - 1);
    float mc[4];
#pragma unroll
    for (int r = 0; r < 4; ++r) mc[r] = -1e30f;
#pragma unroll
    for (int ni = 0; ni < 4; ++ni)
#pragma unroll
      for (int r = 0; r < 4; ++r) {
        float sv = s[ni][r] * 0.125f;  // 1/sqrt(64)
        if (diag && (k0 + ni * 16 + lr > q0 + w * 16 + g * 4 + r)) sv = -1e30f;
        s[ni][r] = sv;
        mc[r] = fmaxf(mc[r], sv);
      }
    // row max across the 16-lane group
#pragma unroll
    for (int mask = 1; mask < 16; mask <<= 1)
#pragma unroll
      for (int r = 0; r < 4; ++r) mc[r] = fmaxf(mc[r], __shfl_xor(mc[r], mask));
    float alpha[4], ls[4];
#pragma unroll
    for (int r = 0; r < 4; ++r) {
      float mnew = fmaxf(m_i[r], mc[r]);
      alpha[r] = __expf(m_i[r] - mnew);
      m_i[r] = mnew;
      ls[r] = 0.f;
    }
#pragma unroll
    for (int ni = 0; ni < 4; ++ni)
#pragma unroll
      for (int r = 0; r < 4; ++r) {
        float p = __expf(s[ni][r] - m_i[r]);
        s[ni][r] = p;
        ls[r] += p;
      }
#pragma unroll
    for (int mask = 1; mask < 16; mask <<= 1)
#pragma unroll
      for (int r = 0; r < 4; ++r) ls[r] += __shfl_xor(ls[r], mask);
#pragma unroll
    for (int r = 0; r < 4; ++r) l_i[r] = l_i[r] * alpha[r] + ls[r];
#pragma unroll
    for (int di = 0; di < 4; ++di)
#pragma unroll
      for (int r = 0; r < 4; ++r) o[di][r] *= alpha[r];

    // P -> LDS (bf16), per-wave buffer: row = g*4+r, col = ni*16+lr
#pragma unroll
    for (int ni = 0; ni < 4; ++ni)
#pragma unroll
      for (int r = 0; r < 4; ++r)
        Pl[w][(g * 4 + r) * KP + ni * 16 + lr] = (short)f2bf(s[ni][r]);
    __syncthreads();

    // O += P @ V
#pragma unroll
    for (int kk = 0; kk < 2; ++kk) {
      short8 pf = *reinterpret_cast<const short8*>(&Pl[w][lr * KP + kk * 32 + g * 8]);
#pragma unroll
      for (int di = 0; di < 4; ++di) {
        short8 vf = *reinterpret_cast<const short8*>(&Vt[(di * 16 + lr) * KP + kk * 32 + g * 8]);
        o[di] = MFMA_BF16(pf, vf, o[di], 0, 0, 0);
      }
    }
  }

  // normalize and scatter to (B,T,D) bf16
  const int b_ = bh >> 4, h_ = bh & 15;
#pragma unroll
  for (int di = 0; di < 4; ++di)
#pragma unroll
    for (int r = 0; r < 4; ++r) {
      float ov = o[di][r] / l_i[r];
      int qg = q0 + w * 16 + g * 4 + r;
      int d_ = di * 16 + lr;
      Og[((size_t)b_ * Tm + qg) * Dm + h_ * HDm + d_] = (short)f2bf(ov);
    }
}

extern "C" void kernel_launch(void* const* d_in, const int* in_sizes, int n_in,
                              void* d_out, int out_size, void* d_ws, size_t ws_size,
                              hipStream_t stream) {
  const float* X = (const float*)d_in[0];
  const float* Wq = (const float*)d_in[1];
  const float* Wk = (const float*)d_in[2];
  const float* Wv = (const float*)d_in[3];
  const float* Wo = (const float*)d_in[4];
  const float* bo = (const float*)d_in[5];
  float* out = (float*)d_out;

  char* ws = (char*)d_ws;
  short* Xb = (short*)ws;  ws += (size_t)Mtot * Dm * 2;
  short* Wqb = (short*)ws; ws += (size_t)Dm * Dm * 2;
  short* Wkb = (short*)ws; ws += (size_t)Dm * Dm * 2;
  short* Wvb = (short*)ws; ws += (size_t)Dm * Dm * 2;
  short* Wob = (short*)ws; ws += (size_t)Dm * Dm * 2;
  short* Qb = (short*)ws;  ws += (size_t)Mtot * Dm * 2;
  short* Kb = (short*)ws;  ws += (size_t)Mtot * Dm * 2;
  short* Vb = (short*)ws;  ws += (size_t)Mtot * Dm * 2;
  short* Ab = (short*)ws;  ws += (size_t)Mtot * Dm * 2;

  cvt_kernel<<<dim3(1024), dim3(256), 0, stream>>>(X, Xb, Mtot * Dm);
  cvt_kernel<<<dim3(256), dim3(256), 0, stream>>>(Wq, Wqb, Dm * Dm);
  cvt_kernel<<<dim3(256), dim3(256), 0, stream>>>(Wk, Wkb, Dm * Dm);
  cvt_kernel<<<dim3(256), dim3(256), 0, stream>>>(Wv, Wvb, Dm * Dm);
  cvt_kernel<<<dim3(256), dim3(256), 0, stream>>>(Wo, Wob, Dm * Dm);

  dim3 ggrid(Dm / 128, Mtot / 128);  // (8, 64)
  gemm128_kernel<0><<<ggrid, 256, 0, stream>>>(Xb, Wqb, Qb, nullptr, nullptr);
  gemm128_kernel<0><<<ggrid, 256, 0, stream>>>(Xb, Wkb, Kb, nullptr, nullptr);
  gemm128_kernel<0><<<ggrid, 256, 0, stream>>>(Xb, Wvb, Vb, nullptr, nullptr);

  attn_kernel<<<dim3(Tm / 64, Bb * NHm), 256, 0, stream>>>(Qb, Kb, Vb, Ab);

  gemm128_kernel<1><<<ggrid, 256, 0, stream>>>(Ab, Wob, nullptr, out, bo);
}

// Round 2
// 361.764 us; speedup vs baseline: 1.8288x; 1.8288x over previous
//
#include <hip/hip_runtime.h>
#include <hip/hip_bf16.h>
#include <math.h>

typedef __attribute__((ext_vector_type(8))) short short8;
typedef __attribute__((ext_vector_type(4))) float f32x4;

#define MFMA_BF16 __builtin_amdgcn_mfma_f32_16x16x32_bf16

static constexpr int Dm = 1024;
static constexpr int Tm = 2048;
static constexpr int Bb = 4;
static constexpr int NHm = 16;
static constexpr int HDm = 64;
static constexpr int Mtot = Bb * Tm;  // 8192

__device__ __forceinline__ unsigned short f2bf(float f) {
  unsigned int u = __float_as_uint(f);
  u += 0x7FFFu + ((u >> 16) & 1u);  // RNE
  return (unsigned short)(u >> 16);
}

__device__ __forceinline__ void gload16(const void* g, void* l) {
  __builtin_amdgcn_global_load_lds((const __attribute__((address_space(1))) void*)g,
                                   (__attribute__((address_space(3))) void*)l, 16, 0, 0);
}

// fp32 -> bf16, vectorized
__global__ __launch_bounds__(256) void cvt_kernel(const float* __restrict__ src,
                                                  short* __restrict__ dst, int n) {
  int stride = gridDim.x * blockDim.x;
  for (int i = blockIdx.x * blockDim.x + threadIdx.x; i * 4 < n; i += stride) {
    float4 v = reinterpret_cast<const float4*>(src)[i];
    short4 o;
    o.x = (short)f2bf(v.x);
    o.y = (short)f2bf(v.y);
    o.z = (short)f2bf(v.z);
    o.w = (short)f2bf(v.w);
    reinterpret_cast<short4*>(dst)[i] = o;
  }
}

// fused fp32->bf16 + transpose for the four 1024x1024 weights: Wt[n][k] = W[k][n]
__global__ __launch_bounds__(256) void cvt_t_kernel(
    const float* __restrict__ W0, const float* __restrict__ W1,
    const float* __restrict__ W2, const float* __restrict__ W3,
    short* __restrict__ T0, short* __restrict__ T1,
    short* __restrict__ T2, short* __restrict__ T3) {
  const float* W = blockIdx.z == 0 ? W0 : blockIdx.z == 1 ? W1 : blockIdx.z == 2 ? W2 : W3;
  short* Wt = blockIdx.z == 0 ? T0 : blockIdx.z == 1 ? T1 : blockIdx.z == 2 ? T2 : T3;
  __shared__ __align__(16) short T[64 * 72];
  const int tid = threadIdx.x;
  const int k0 = blockIdx.y * 64, n0 = blockIdx.x * 64;
#pragma unroll
  for (int p = 0; p < 4; ++p) {
    int idx = tid + p * 256;
    int kr = idx >> 4, c4 = (idx & 15) * 4;
    float4 v = *reinterpret_cast<const float4*>(W + (size_t)(k0 + kr) * Dm + n0 + c4);
    T[(c4 + 0) * 72 + kr] = (short)f2bf(v.x);
    T[(c4 + 1) * 72 + kr] = (short)f2bf(v.y);
    T[(c4 + 2) * 72 + kr] = (short)f2bf(v.z);
    T[(c4 + 3) * 72 + kr] = (short)f2bf(v.w);
  }
  __syncthreads();
#pragma unroll
  for (int p = 0; p < 2; ++p) {
    int idx = tid + p * 256;
    int nr = idx >> 3, c8 = (idx & 7) * 8;
    *reinterpret_cast<short8*>(Wt + (size_t)(n0 + nr) * Dm + k0 + c8) =
        *reinterpret_cast<const short8*>(&T[nr * 72 + c8]);
  }
}

// C = A(M x 1024 bf16 row-major) @ Bt^T where Bt is [N][K] bf16 row-major.
// m97 structure: 128x128 tile, BK=32, global_load_lds width 16, linear LDS.
// MODE 0: scatter bf16 to (B,H,T,hd); MODE 1: fp32 + bias to row-major C.
template <int MODE>
__global__ __launch_bounds__(256) void gemm_bt_kernel(
    const short* __restrict__ Ags, const short* __restrict__ Bts,
    short* __restrict__ Cbf, float* __restrict__ Cf, const float* __restrict__ bias) {
  __shared__ __align__(16) short As[128 * 32];
  __shared__ __align__(16) short Bs[128 * 32];
  const int tid = threadIdx.x;
  const int lane = tid & 63;
  const int w = tid >> 6;
  const int wr = (w >> 1) * 64, wc = (w & 1) * 64;
  const int g = lane >> 4;
  const int lr = lane & 15;
  const int m0 = blockIdx.y * 128;
  const int n0 = blockIdx.x * 128;
  const int rowt = tid >> 2;          // 0..63
  const int cg8 = (tid & 3) * 8;      // col group (shorts)

  f32x4 acc[4][4];
#pragma unroll
  for (int mi = 0; mi < 4; ++mi)
#pragma unroll
    for (int ni = 0; ni < 4; ++ni)
#pragma unroll
      for (int r = 0; r < 4; ++r) acc[mi][ni][r] = 0.f;

  for (int kt = 0; kt < Dm / 32; ++kt) {
    __syncthreads();
#pragma unroll
    for (int p = 0; p < 2; ++p) {
      // wave-uniform LDS base + lane*16 (HW rule); per-lane global address
      gload16(Ags + (size_t)(m0 + p * 64 + rowt) * Dm + kt * 32 + cg8,
              &As[(p * 64 + w * 16) * 32]);
      gload16(Bts + (size_t)(n0 + p * 64 + rowt) * Dm + kt * 32 + cg8,
              &Bs[(p * 64 + w * 16) * 32]);
    }
    __syncthreads();
    short8 a[4], b[4];
#pragma unroll
    for (int mi = 0; mi < 4; ++mi)
      a[mi] = *reinterpret_cast<const short8*>(&As[(wr + mi * 16 + lr) * 32 + g * 8]);
#pragma unroll
    for (int ni = 0; ni < 4; ++ni)
      b[ni] = *reinterpret_cast<const short8*>(&Bs[(wc + ni * 16 + lr) * 32 + g * 8]);
#pragma unroll
    for (int mi = 0; mi < 4; ++mi)
#pragma unroll
      for (int ni = 0; ni < 4; ++ni)
        acc[mi][ni] = MFMA_BF16(a[mi], b[ni], acc[mi][ni], 0, 0, 0);
  }

#pragma unroll
  for (int mi = 0; mi < 4; ++mi)
#pragma unroll
    for (int ni = 0; ni < 4; ++ni)
#pragma unroll
      for (int r = 0; r < 4; ++r) {
        int mg = m0 + wr + mi * 16 + g * 4 + r;  // C/D: row=(lane>>4)*4+reg
        int ng = n0 + wc + ni * 16 + lr;         // C/D: col=lane&15
        float v = acc[mi][ni][r];
        if (MODE == 0) {
          int b_ = mg >> 11, t_ = mg & 2047, h_ = ng >> 6, d_ = ng & 63;
          Cbf[(((size_t)(b_ * NHm + h_) * Tm) + t_) * HDm + d_] = (short)f2bf(v);
        } else {
          Cf[(size_t)mg * Dm + ng] = v + bias[ng];
        }
      }
}

// Flash attention, causal. Block = one (b,h) x 128 queries; 4 waves x 32 q-rows.
__global__ __launch_bounds__(256) void attn_kernel(
    const short* __restrict__ Qg, const short* __restrict__ Kg,
    const short* __restrict__ Vg, short* __restrict__ Og) {
  constexpr int KP = 72;  // pitch (shorts): 36 banks -> conflict-free column reads
  __shared__ __align__(16) short Kl[64 * KP];       // [key][d]
  __shared__ __align__(16) short Vt[64 * KP];       // [d][key ^ swz]
  __shared__ __align__(16) short Pl[4 * 32 * KP];   // per-wave [q][key]
  const int tid = threadIdx.x;
  const int lane = tid & 63;
  const int w = tid >> 6;
  const int g = lane >> 4;
  const int lr = lane & 15;
  const int bh = blockIdx.y;
  const int qb = gridDim.x - 1 - blockIdx.x;  // heavy blocks first
  const int q0 = qb * 128;
  const int qw = q0 + w * 32;  // wave's first q row
  const short* Qs = Qg + ((size_t)bh * Tm + q0) * HDm;
  const short* Ks = Kg + (size_t)bh * Tm * HDm;
  const short* Vs = Vg + (size_t)bh * Tm * HDm;
  short* Pw = &Pl[w * 32 * KP];

  // Q fragments in registers: row = w*32 + mi*16 + lr, k = kk*32 + g*8 + j
  short8 qf[2][2];
#pragma unroll
  for (int mi = 0; mi < 2; ++mi)
#pragma unroll
    for (int kk = 0; kk < 2; ++kk)
      qf[mi][kk] = *reinterpret_cast<const short8*>(
          Qs + (w * 32 + mi * 16 + lr) * HDm + kk * 32 + g * 8);

  f32x4 o[2][4];
  float m_i[2][4], l_i[2][4];
#pragma unroll
  for (int mi = 0; mi < 2; ++mi)
#pragma unroll
    for (int r = 0; r < 4; ++r) {
      m_i[mi][r] = -1e30f;
      l_i[mi][r] = 0.f;
#pragma unroll
      for (int di = 0; di < 4; ++di) o[mi][di][r] = 0.f;
    }

  const int nt = q0 / 64 + 2;
  for (int t = 0; t < nt; ++t) {
    const int k0 = t * 64;
    __syncthreads();  // protect K/V from previous iteration's readers
    // stage K row-major; V transposed with XOR-swizzled key index (bank spread)
#pragma unroll
    for (int p = 0; p < 2; ++p) {
      int idx = tid + p * 256;
      int kr = idx >> 3, c8 = (idx & 7) * 8;
      short8 kv = *reinterpret_cast<const short8*>(Ks + (size_t)(k0 + kr) * HDm + c8);
      *reinterpret_cast<short8*>(&Kl[kr * KP + c8]) = kv;
      short8 vv = *reinterpret_cast<const short8*>(Vs + (size_t)(k0 + kr) * HDm + c8);
#pragma unroll
      for (int i = 0; i < 8; ++i) {
        int d = c8 + i;
        Vt[d * KP + (kr ^ (((d >> 3) & 7) << 3))] = vv[i];
      }
    }
    __syncthreads();

    const bool active = (k0 <= qw);  // k0, qw both mult of 32; else fully masked
    if (active) {
      const bool diag = (k0 + 63 > qw);
#pragma unroll
      for (int mi = 0; mi < 2; ++mi) {
        f32x4 s[4];
#pragma unroll
        for (int ni = 0; ni < 4; ++ni) {
          f32x4 acc;
#pragma unroll
          for (int r = 0; r < 4; ++r) acc[r] = 0.f;
#pragma unroll
          for (int kk = 0; kk < 2; ++kk) {
            short8 kf = *reinterpret_cast<const short8*>(
                &Kl[(ni * 16 + lr) * KP + kk * 32 + g * 8]);
            acc = MFMA_BF16(qf[mi][kk], kf, acc, 0, 0, 0);
          }
          s[ni] = acc;
        }
        float mc[4];
#pragma unroll
        for (int r = 0; r < 4; ++r) mc[r] = -1e30f;
#pragma unroll
        for (int ni = 0; ni < 4; ++ni)
#pragma unroll
          for (int r = 0; r < 4; ++r) {
            float sv = s[ni][r] * 0.125f;  // 1/sqrt(64)
            if (diag && (k0 + ni * 16 + lr > qw + mi * 16 + g * 4 + r)) sv = -1e30f;
            s[ni][r] = sv;
            mc[r] = fmaxf(mc[r], sv);
          }
#pragma unroll
        for (int mask = 1; mask < 16; mask <<= 1)
#pragma unroll
          for (int r = 0; r < 4; ++r) mc[r] = fmaxf(mc[r], __shfl_xor(mc[r], mask));
        float alpha[4], ls[4];
#pragma unroll
        for (int r = 0; r < 4; ++r) {
          float mnew = fmaxf(m_i[mi][r], mc[r]);
          alpha[r] = __expf(m_i[mi][r] - mnew);
          m_i[mi][r] = mnew;
          ls[r] = 0.f;
        }
#pragma unroll
        for (int ni = 0; ni < 4; ++ni)
#pragma unroll
          for (int r = 0; r < 4; ++r) {
            float p = __expf(s[ni][r] - m_i[mi][r]);
            s[ni][r] = p;
            ls[r] += p;
          }
#pragma unroll
        for (int mask = 1; mask < 16; mask <<= 1)
#pragma unroll
          for (int r = 0; r < 4; ++r) ls[r] += __shfl_xor(ls[r], mask);
#pragma unroll
        for (int r = 0; r < 4; ++r) l_i[mi][r] = l_i[mi][r] * alpha[r] + ls[r];
#pragma unroll
        for (int di = 0; di < 4; ++di)
#pragma unroll
          for (int r = 0; r < 4; ++r) o[mi][di][r] *= alpha[r];
        // P -> per-wave LDS (no cross-wave barrier needed)
#pragma unroll
        for (int ni = 0; ni < 4; ++ni)
#pragma unroll
          for (int r = 0; r < 4; ++r)
            Pw[(mi * 16 + g * 4 + r) * KP + ni * 16 + lr] = (short)f2bf(s[ni][r]);
      }

      // O += P @ V  (V read through the same XOR swizzle)
#pragma unroll
      for (int kk = 0; kk < 2; ++kk) {
        short8 pf[2];
#pragma unroll
        for (int mi = 0; mi < 2; ++mi)
          pf[mi] = *reinterpret_cast<const short8*>(
              &Pw[(mi * 16 + lr) * KP + kk * 32 + g * 8]);
#pragma unroll
        for (int di = 0; di < 4; ++di) {
          int d = di * 16 + lr;
          short8 vf = *reinterpret_cast<const short8*>(
              &Vt[d * KP + (((kk * 4 + g) ^ ((d >> 3) & 7)) << 3)]);
#pragma unroll
          for (int mi = 0; mi < 2; ++mi)
            o[mi][di] = MFMA_BF16(pf[mi], vf, o[mi][di], 0, 0, 0);
        }
      }
    }
  }

  // normalize, scatter to (B,T,D) bf16
  const int b_ = bh >> 4, h_ = bh & 15;
#pragma unroll
  for (int mi = 0; mi < 2; ++mi)
#pragma unroll
    for (int di = 0; di < 4; ++di)
#pragma unroll
      for (int r = 0; r < 4; ++r) {
        float ov = o[mi][di][r] / l_i[mi][r];
        int qg = q0 + w * 32 + mi * 16 + g * 4 + r;
        int d_ = di * 16 + lr;
        Og[((size_t)b_ * Tm + qg) * Dm + h_ * HDm + d_] = (short)f2bf(ov);
      }
}

extern "C" void kernel_launch(void* const* d_in, const int* in_sizes, int n_in,
                              void* d_out, int out_size, void* d_ws, size_t ws_size,
                              hipStream_t stream) {
  const float* X = (const float*)d_in[0];
  const float* Wq = (const float*)d_in[1];
  const float* Wk = (const float*)d_in[2];
  const float* Wv = (const float*)d_in[3];
  const float* Wo = (const float*)d_in[4];
  const float* bo = (const float*)d_in[5];
  float* out = (float*)d_out;

  char* ws = (char*)d_ws;
  short* Xb = (short*)ws;  ws += (size_t)Mtot * Dm * 2;
  short* Wqt = (short*)ws; ws += (size_t)Dm * Dm * 2;
  short* Wkt = (short*)ws; ws += (size_t)Dm * Dm * 2;
  short* Wvt = (short*)ws; ws += (size_t)Dm * Dm * 2;
  short* Wot = (short*)ws; ws += (size_t)Dm * Dm * 2;
  short* Qb = (short*)ws;  ws += (size_t)Mtot * Dm * 2;
  short* Kb = (short*)ws;  ws += (size_t)Mtot * Dm * 2;
  short* Vb = (short*)ws;  ws += (size_t)Mtot * Dm * 2;
  short* Ab = (short*)ws;  ws += (size_t)Mtot * Dm * 2;

  cvt_kernel<<<dim3(1024), dim3(256), 0, stream>>>(X, Xb, Mtot * Dm);
  cvt_t_kernel<<<dim3(16, 16, 4), dim3(256), 0, stream>>>(Wq, Wk, Wv, Wo, Wqt, Wkt, Wvt, Wot);

  dim3 ggrid(Dm / 128, Mtot / 128);  // (8, 64)
  gemm_bt_kernel<0><<<ggrid, 256, 0, stream>>>(Xb, Wqt, Qb, nullptr, nullptr);
  gemm_bt_kernel<0><<<ggrid, 256, 0, stream>>>(Xb, Wkt, Kb, nullptr, nullptr);
  gemm_bt_kernel<0><<<ggrid, 256, 0, stream>>>(Xb, Wvt, Vb, nullptr, nullptr);

  attn_kernel<<<dim3(Tm / 128, Bb * NHm), 256, 0, stream>>>(Qb, Kb, Vb, Ab);

  gemm_bt_kernel<1><<<ggrid, 256, 0, stream>>>(Ab, Wot, nullptr, out, bo);
}

// Round 3
// 276.100 us; speedup vs baseline: 2.3963x; 1.3103x over previous
//
#include <hip/hip_runtime.h>
#include <hip/hip_bf16.h>
#include <math.h>

typedef __attribute__((ext_vector_type(8))) short short8;
typedef __attribute__((ext_vector_type(4))) float f32x4;

#define MFMA_BF16 __builtin_amdgcn_mfma_f32_16x16x32_bf16

static constexpr int Dm = 1024;
static constexpr int Tm = 2048;
static constexpr int Bb = 4;
static constexpr int NHm = 16;
static constexpr int HDm = 64;
static constexpr int Mtot = Bb * Tm;   // 8192
static constexpr int NKT = Tm / 64;    // 32 KV tiles per (b,h)
static constexpr float kQScale = 0.125f * 1.4426950408889634f;  // 1/sqrt(64) * log2(e)

__device__ __forceinline__ unsigned short f2bf(float f) {
  unsigned int u = __float_as_uint(f);
  u += 0x7FFFu + ((u >> 16) & 1u);  // RNE
  return (unsigned short)(u >> 16);
}

__device__ __forceinline__ void gload16(const void* g, void* l) {
  __builtin_amdgcn_global_load_lds((const __attribute__((address_space(1))) void*)g,
                                   (__attribute__((address_space(3))) void*)l, 16, 0, 0);
}

__global__ __launch_bounds__(256) void cvt_kernel(const float* __restrict__ src,
                                                  short* __restrict__ dst, int n) {
  int stride = gridDim.x * blockDim.x;
  for (int i = blockIdx.x * blockDim.x + threadIdx.x; i * 4 < n; i += stride) {
    float4 v = reinterpret_cast<const float4*>(src)[i];
    short4 o;
    o.x = (short)f2bf(v.x);
    o.y = (short)f2bf(v.y);
    o.z = (short)f2bf(v.z);
    o.w = (short)f2bf(v.w);
    reinterpret_cast<short4*>(dst)[i] = o;
  }
}

// fused fp32->bf16 + transpose: Wt[n][k] = W[k][n], for all four weights
__global__ __launch_bounds__(256) void cvt_t_kernel(
    const float* __restrict__ W0, const float* __restrict__ W1,
    const float* __restrict__ W2, const float* __restrict__ W3,
    short* __restrict__ T0, short* __restrict__ T1,
    short* __restrict__ T2, short* __restrict__ T3) {
  const float* W = blockIdx.z == 0 ? W0 : blockIdx.z == 1 ? W1 : blockIdx.z == 2 ? W2 : W3;
  short* Wt = blockIdx.z == 0 ? T0 : blockIdx.z == 1 ? T1 : blockIdx.z == 2 ? T2 : T3;
  __shared__ __align__(16) short T[64 * 72];
  const int tid = threadIdx.x;
  const int k0 = blockIdx.y * 64, n0 = blockIdx.x * 64;
#pragma unroll
  for (int p = 0; p < 4; ++p) {
    int idx = tid + p * 256;
    int kr = idx >> 4, c4 = (idx & 15) * 4;
    float4 v = *reinterpret_cast<const float4*>(W + (size_t)(k0 + kr) * Dm + n0 + c4);
    T[(c4 + 0) * 72 + kr] = (short)f2bf(v.x);
    T[(c4 + 1) * 72 + kr] = (short)f2bf(v.y);
    T[(c4 + 2) * 72 + kr] = (short)f2bf(v.z);
    T[(c4 + 3) * 72 + kr] = (short)f2bf(v.w);
  }
  __syncthreads();
#pragma unroll
  for (int p = 0; p < 2; ++p) {
    int idx = tid + p * 256;
    int nr = idx >> 3, c8 = (idx & 7) * 8;
    *reinterpret_cast<short8*>(Wt + (size_t)(n0 + nr) * Dm + k0 + c8) =
        *reinterpret_cast<const short8*>(&T[nr * 72 + c8]);
  }
}

// C = A(M x 1024 bf16 rm) @ Bt^T, Bt is [N][K] bf16 rm. m97 structure.
// MODE 0: Q  -> bf16 row-major (bh,t,d), pre-scaled by kQScale
// MODE 1: K  -> bf16 tiled [bh][kt][kr][d ^ ((kr&7)<<3)]   (LDS image)
// MODE 2: V^T-> bf16 tiled [bh][kt][d][kr ^ ((d&7)<<3)]    (LDS image)
// MODE 3: fp32 + bias, row-major
template <int MODE>
__global__ __launch_bounds__(256) void gemm_bt_kernel(
    const short* __restrict__ Ags, const short* __restrict__ Bts,
    short* __restrict__ Cbf, float* __restrict__ Cf, const float* __restrict__ bias) {
  __shared__ __align__(16) short As[128 * 32];
  __shared__ __align__(16) short Bs[128 * 32];
  const int tid = threadIdx.x;
  const int lane = tid & 63;
  const int w = tid >> 6;
  const int wr = (w >> 1) * 64, wc = (w & 1) * 64;
  const int g = lane >> 4;
  const int lr = lane & 15;
  const int m0 = blockIdx.y * 128;
  const int n0 = blockIdx.x * 128;
  const int rowt = tid >> 2;
  const int cg8 = (tid & 3) * 8;

  f32x4 acc[4][4];
#pragma unroll
  for (int mi = 0; mi < 4; ++mi)
#pragma unroll
    for (int ni = 0; ni < 4; ++ni)
#pragma unroll
      for (int r = 0; r < 4; ++r) acc[mi][ni][r] = 0.f;

  for (int kt = 0; kt < Dm / 32; ++kt) {
    __syncthreads();
#pragma unroll
    for (int p = 0; p < 2; ++p) {
      gload16(Ags + (size_t)(m0 + p * 64 + rowt) * Dm + kt * 32 + cg8,
              &As[(p * 64 + w * 16) * 32]);
      gload16(Bts + (size_t)(n0 + p * 64 + rowt) * Dm + kt * 32 + cg8,
              &Bs[(p * 64 + w * 16) * 32]);
    }
    __syncthreads();
    short8 a[4], b[4];
#pragma unroll
    for (int mi = 0; mi < 4; ++mi)
      a[mi] = *reinterpret_cast<const short8*>(&As[(wr + mi * 16 + lr) * 32 + g * 8]);
#pragma unroll
    for (int ni = 0; ni < 4; ++ni)
      b[ni] = *reinterpret_cast<const short8*>(&Bs[(wc + ni * 16 + lr) * 32 + g * 8]);
#pragma unroll
    for (int mi = 0; mi < 4; ++mi)
#pragma unroll
      for (int ni = 0; ni < 4; ++ni)
        acc[mi][ni] = MFMA_BF16(a[mi], b[ni], acc[mi][ni], 0, 0, 0);
  }

#pragma unroll
  for (int mi = 0; mi < 4; ++mi)
#pragma unroll
    for (int ni = 0; ni < 4; ++ni)
#pragma unroll
      for (int r = 0; r < 4; ++r) {
        int mg = m0 + wr + mi * 16 + g * 4 + r;  // C/D: row=(lane>>4)*4+reg
        int ng = n0 + wc + ni * 16 + lr;         // C/D: col=lane&15
        float v = acc[mi][ni][r];
        int b_ = mg >> 11, t_ = mg & 2047, h_ = ng >> 6, d_ = ng & 63;
        size_t bh = (size_t)(b_ * NHm + h_);
        if (MODE == 0) {
          Cbf[(bh * Tm + t_) * HDm + d_] = (short)f2bf(v * kQScale);
        } else if (MODE == 1) {
          Cbf[((bh * NKT + (t_ >> 6)) << 12) + (t_ & 63) * 64 + (d_ ^ ((t_ & 7) << 3))] =
              (short)f2bf(v);
        } else if (MODE == 2) {
          Cbf[((bh * NKT + (t_ >> 6)) << 12) + d_ * 64 + ((t_ & 63) ^ ((d_ & 7) << 3))] =
              (short)f2bf(v);
        } else {
          Cf[(size_t)mg * Dm + ng] = v + bias[ng];
        }
      }
}

// Flash attention, causal. Block = (pair, bh); processes q-tiles pi and 15-pi
// (128 queries each, 4 waves x 32 rows) -> every block = 34 stage-iters.
// K/V staged from pre-swizzled global tiles via global_load_lds, double-buffered.
__global__ __launch_bounds__(256) void attn_kernel(
    const short* __restrict__ Qg, const short* __restrict__ Kg,
    const short* __restrict__ Vg, short* __restrict__ Og) {
  __shared__ __align__(16) short Kl[2][64 * 64];
  __shared__ __align__(16) short Vl[2][64 * 64];
  __shared__ __align__(16) short Pl[4][32 * 72];
  const int tid = threadIdx.x;
  const int lane = tid & 63;
  const int w = tid >> 6;
  const int g = lane >> 4;
  const int lr = lane & 15;
  const int bh = blockIdx.y;
  const int pi = blockIdx.x;
  const short* Ks = Kg + ((size_t)bh * NKT << 12);
  const short* Vs = Vg + ((size_t)bh * NKT << 12);
  short* Pw = &Pl[w][0];
  const int b_ = bh >> 4, h_ = bh & 15;

  auto stage = [&](int t, int buf) {
#pragma unroll
    for (int i = 0; i < 2; ++i) {
      int ch = w * 2 + i;  // 8 chunks of 1024B per 8KB tile
      gload16(Ks + ((size_t)t << 12) + ch * 512 + lane * 8, &Kl[buf][ch * 512]);
      gload16(Vs + ((size_t)t << 12) + ch * 512 + lane * 8, &Vl[buf][ch * 512]);
    }
  };

  for (int pass = 0; pass < 2; ++pass) {
    const int qb = pass == 0 ? (15 - pi) : pi;  // heavy pass first
    const int q0 = qb * 128;
    const int qw = q0 + w * 32;
    const short* Qs = Qg + ((size_t)bh * Tm + q0) * HDm;

    short8 qf[2][2];
#pragma unroll
    for (int mi = 0; mi < 2; ++mi)
#pragma unroll
      for (int kk = 0; kk < 2; ++kk)
        qf[mi][kk] = *reinterpret_cast<const short8*>(
            Qs + (w * 32 + mi * 16 + lr) * HDm + kk * 32 + g * 8);

    f32x4 o[2][4];
    float m_i[2][4], l_i[2][4];
#pragma unroll
    for (int mi = 0; mi < 2; ++mi)
#pragma unroll
      for (int r = 0; r < 4; ++r) {
        m_i[mi][r] = -1e30f;
        l_i[mi][r] = 0.f;
#pragma unroll
        for (int di = 0; di < 4; ++di) o[mi][di][r] = 0.f;
      }

    const int nt = q0 / 64 + 2;
    stage(0, 0);
    __syncthreads();  // buf0 ready (compiler drains vmcnt before barrier)
    int cur = 0;
    for (int t = 0; t < nt; ++t) {
      if (t + 1 < nt) stage(t + 1, cur ^ 1);  // in flight during compute
      const int k0 = t * 64;
      const bool active = (k0 <= qw + 31);
      if (active) {
        const bool diag = (k0 + 63 > qw);
        // hoisted K fragments (swizzle is an involution on 8-short blocks)
        short8 kf[2][4];
#pragma unroll
        for (int ni = 0; ni < 4; ++ni) {
          int row = ni * 16 + lr;
#pragma unroll
          for (int kk = 0; kk < 2; ++kk)
            kf[kk][ni] = *reinterpret_cast<const short8*>(
                &Kl[cur][row * 64 + ((kk * 32 + g * 8) ^ ((row & 7) << 3))]);
        }
#pragma unroll
        for (int mi = 0; mi < 2; ++mi) {
          f32x4 s[4];
#pragma unroll
          for (int ni = 0; ni < 4; ++ni) {
            f32x4 acc;
#pragma unroll
            for (int r = 0; r < 4; ++r) acc[r] = 0.f;
            acc = MFMA_BF16(qf[mi][0], kf[0][ni], acc, 0, 0, 0);
            acc = MFMA_BF16(qf[mi][1], kf[1][ni], acc, 0, 0, 0);
            s[ni] = acc;
          }
          float mc[4];
#pragma unroll
          for (int r = 0; r < 4; ++r) mc[r] = -1e30f;
#pragma unroll
          for (int ni = 0; ni < 4; ++ni)
#pragma unroll
            for (int r = 0; r < 4; ++r) {
              float sv = s[ni][r];  // already scaled to log2 units via Q
              if (diag && (k0 + ni * 16 + lr > qw + mi * 16 + g * 4 + r)) sv = -1e30f;
              s[ni][r] = sv;
              mc[r] = fmaxf(mc[r], sv);
            }
#pragma unroll
          for (int mask = 1; mask < 16; mask <<= 1)
#pragma unroll
            for (int r = 0; r < 4; ++r) mc[r] = fmaxf(mc[r], __shfl_xor(mc[r], mask));
          float alpha[4], ls[4];
#pragma unroll
          for (int r = 0; r < 4; ++r) {
            float mnew = fmaxf(m_i[mi][r], mc[r]);
            alpha[r] = exp2f(m_i[mi][r] - mnew);
            m_i[mi][r] = mnew;
            ls[r] = 0.f;
          }
#pragma unroll
          for (int ni = 0; ni < 4; ++ni)
#pragma unroll
            for (int r = 0; r < 4; ++r) {
              float p = exp2f(s[ni][r] - m_i[mi][r]);
              s[ni][r] = p;
              ls[r] += p;
            }
#pragma unroll
          for (int mask = 1; mask < 16; mask <<= 1)
#pragma unroll
            for (int r = 0; r < 4; ++r) ls[r] += __shfl_xor(ls[r], mask);
#pragma unroll
          for (int r = 0; r < 4; ++r) l_i[mi][r] = l_i[mi][r] * alpha[r] + ls[r];
#pragma unroll
          for (int di = 0; di < 4; ++di)
#pragma unroll
            for (int r = 0; r < 4; ++r) o[mi][di][r] *= alpha[r];
#pragma unroll
          for (int ni = 0; ni < 4; ++ni)
#pragma unroll
            for (int r = 0; r < 4; ++r)
              Pw[(mi * 16 + g * 4 + r) * 72 + ni * 16 + lr] = (short)f2bf(s[ni][r]);
        }

        // O += P @ V (V^T in LDS, swizzled cols)
#pragma unroll
        for (int kk = 0; kk < 2; ++kk) {
          short8 pf[2];
#pragma unroll
          for (int mi = 0; mi < 2; ++mi)
            pf[mi] = *reinterpret_cast<const short8*>(
                &Pw[(mi * 16 + lr) * 72 + kk * 32 + g * 8]);
#pragma unroll
          for (int di = 0; di < 4; ++di) {
            int d = di * 16 + lr;
            short8 vf = *reinterpret_cast<const short8*>(
                &Vl[cur][d * 64 + ((kk * 32 + g * 8) ^ ((d & 7) << 3))]);
#pragma unroll
            for (int mi = 0; mi < 2; ++mi)
              o[mi][di] = MFMA_BF16(pf[mi], vf, o[mi][di], 0, 0, 0);
          }
        }
      }
      __syncthreads();  // drains stage(t+1); protects buf reuse + pass restart
      cur ^= 1;
    }

    // normalize, scatter to (B,T,D) bf16
#pragma unroll
    for (int mi = 0; mi < 2; ++mi)
#pragma unroll
      for (int di = 0; di < 4; ++di)
#pragma unroll
        for (int r = 0; r < 4; ++r) {
          float ov = o[mi][di][r] / l_i[mi][r];
          int qg = q0 + w * 32 + mi * 16 + g * 4 + r;
          int d_ = di * 16 + lr;
          Og[((size_t)b_ * Tm + qg) * Dm + h_ * HDm + d_] = (short)f2bf(ov);
        }
  }
}

extern "C" void kernel_launch(void* const* d_in, const int* in_sizes, int n_in,
                              void* d_out, int out_size, void* d_ws, size_t ws_size,
                              hipStream_t stream) {
  const float* X = (const float*)d_in[0];
  const float* Wq = (const float*)d_in[1];
  const float* Wk = (const float*)d_in[2];
  const float* Wv = (const float*)d_in[3];
  const float* Wo = (const float*)d_in[4];
  const float* bo = (const float*)d_in[5];
  float* out = (float*)d_out;

  char* ws = (char*)d_ws;
  short* Xb = (short*)ws;  ws += (size_t)Mtot * Dm * 2;
  short* Wqt = (short*)ws; ws += (size_t)Dm * Dm * 2;
  short* Wkt = (short*)ws; ws += (size_t)Dm * Dm * 2;
  short* Wvt = (short*)ws; ws += (size_t)Dm * Dm * 2;
  short* Wot = (short*)ws; ws += (size_t)Dm * Dm * 2;
  short* Qb = (short*)ws;  ws += (size_t)Mtot * Dm * 2;
  short* Kb = (short*)ws;  ws += (size_t)Mtot * Dm * 2;
  short* Vb = (short*)ws;  ws += (size_t)Mtot * Dm * 2;
  short* Ab = (short*)ws;  ws += (size_t)Mtot * Dm * 2;

  cvt_kernel<<<dim3(1024), dim3(256), 0, stream>>>(X, Xb, Mtot * Dm);
  cvt_t_kernel<<<dim3(16, 16, 4), dim3(256), 0, stream>>>(Wq, Wk, Wv, Wo, Wqt, Wkt, Wvt, Wot);

  dim3 ggrid(Dm / 128, Mtot / 128);  // (8, 64)
  gemm_bt_kernel<0><<<ggrid, 256, 0, stream>>>(Xb, Wqt, Qb, nullptr, nullptr);
  gemm_bt_kernel<1><<<ggrid, 256, 0, stream>>>(Xb, Wkt, Kb, nullptr, nullptr);
  gemm_bt_kernel<2><<<ggrid, 256, 0, stream>>>(Xb, Wvt, Vb, nullptr, nullptr);

  attn_kernel<<<dim3(8, Bb * NHm), 256, 0, stream>>>(Qb, Kb, Vb, Ab);

  gemm_bt_kernel<3><<<ggrid, 256, 0, stream>>>(Ab, Wot, nullptr, out, bo);
}

// Round 4
// 211.933 us; speedup vs baseline: 3.1218x; 1.3028x over previous
//
#include <hip/hip_runtime.h>
#include <hip/hip_bf16.h>
#include <math.h>

typedef __attribute__((ext_vector_type(8))) short short8;
typedef __attribute__((ext_vector_type(4))) float f32x4;

#define MFMA_BF16 __builtin_amdgcn_mfma_f32_16x16x32_bf16

static constexpr int Dm = 1024;
static constexpr int Tm = 2048;
static constexpr int Bb = 4;
static constexpr int NHm = 16;
static constexpr int HDm = 64;
static constexpr int Mtot = Bb * Tm;   // 8192
static constexpr int NKT = Tm / 64;    // 32 KV tiles per (b,h)
static constexpr float kQScale = 0.125f * 1.4426950408889634f;  // 1/sqrt(64) * log2(e)

__device__ __forceinline__ unsigned short f2bf(float f) {
  unsigned int u = __float_as_uint(f);
  u += 0x7FFFu + ((u >> 16) & 1u);  // RNE
  return (unsigned short)(u >> 16);
}

__device__ __forceinline__ float fexp2(float x) {  // raw v_exp_f32 (2^x)
  float r;
  asm("v_exp_f32 %0, %1" : "=v"(r) : "v"(x));
  return r;
}

__device__ __forceinline__ void gload16(const void* g, void* l) {
  __builtin_amdgcn_global_load_lds((const __attribute__((address_space(1))) void*)g,
                                   (__attribute__((address_space(3))) void*)l, 16, 0, 0);
}

__global__ __launch_bounds__(256) void cvt_kernel(const float* __restrict__ src,
                                                  short* __restrict__ dst, int n) {
  int stride = gridDim.x * blockDim.x;
  for (int i = blockIdx.x * blockDim.x + threadIdx.x; i * 4 < n; i += stride) {
    float4 v = reinterpret_cast<const float4*>(src)[i];
    short4 o;
    o.x = (short)f2bf(v.x);
    o.y = (short)f2bf(v.y);
    o.z = (short)f2bf(v.z);
    o.w = (short)f2bf(v.w);
    reinterpret_cast<short4*>(dst)[i] = o;
  }
}

// fused fp32->bf16 + transpose: Wt[n][k] = W[k][n], for all four weights
__global__ __launch_bounds__(256) void cvt_t_kernel(
    const float* __restrict__ W0, const float* __restrict__ W1,
    const float* __restrict__ W2, const float* __restrict__ W3,
    short* __restrict__ T0, short* __restrict__ T1,
    short* __restrict__ T2, short* __restrict__ T3) {
  const float* W = blockIdx.z == 0 ? W0 : blockIdx.z == 1 ? W1 : blockIdx.z == 2 ? W2 : W3;
  short* Wt = blockIdx.z == 0 ? T0 : blockIdx.z == 1 ? T1 : blockIdx.z == 2 ? T2 : T3;
  __shared__ __align__(16) short T[64 * 72];
  const int tid = threadIdx.x;
  const int k0 = blockIdx.y * 64, n0 = blockIdx.x * 64;
#pragma unroll
  for (int p = 0; p < 4; ++p) {
    int idx = tid + p * 256;
    int kr = idx >> 4, c4 = (idx & 15) * 4;
    float4 v = *reinterpret_cast<const float4*>(W + (size_t)(k0 + kr) * Dm + n0 + c4);
    T[(c4 + 0) * 72 + kr] = (short)f2bf(v.x);
    T[(c4 + 1) * 72 + kr] = (short)f2bf(v.y);
    T[(c4 + 2) * 72 + kr] = (short)f2bf(v.z);
    T[(c4 + 3) * 72 + kr] = (short)f2bf(v.w);
  }
  __syncthreads();
#pragma unroll
  for (int p = 0; p < 2; ++p) {
    int idx = tid + p * 256;
    int nr = idx >> 3, c8 = (idx & 7) * 8;
    *reinterpret_cast<short8*>(Wt + (size_t)(n0 + nr) * Dm + k0 + c8) =
        *reinterpret_cast<const short8*>(&T[nr * 72 + c8]);
  }
}

// C = A(M x 1024 bf16 rm) @ Bt^T, Bt is [N][K] bf16 rm. m97 structure.
// MODE 0: Q  -> bf16 row-major (bh,t,d), pre-scaled by kQScale (log2 units)
// MODE 1: K  -> bf16 tiled [bh][kt][kr][d ^ ((kr&7)<<3)]   (LDS image)
// MODE 2: V^T-> bf16 tiled [bh][kt][d][kr ^ ((d&7)<<3)]    (LDS image)
// MODE 3: fp32 + bias, row-major
template <int MODE>
__global__ __launch_bounds__(256) void gemm_bt_kernel(
    const short* __restrict__ Ags, const short* __restrict__ Bts,
    short* __restrict__ Cbf, float* __restrict__ Cf, const float* __restrict__ bias) {
  __shared__ __align__(16) short As[128 * 32];
  __shared__ __align__(16) short Bs[128 * 32];
  const int tid = threadIdx.x;
  const int lane = tid & 63;
  const int w = tid >> 6;
  const int wr = (w >> 1) * 64, wc = (w & 1) * 64;
  const int g = lane >> 4;
  const int lr = lane & 15;
  const int m0 = blockIdx.y * 128;
  const int n0 = blockIdx.x * 128;
  const int rowt = tid >> 2;
  const int cg8 = (tid & 3) * 8;

  f32x4 acc[4][4];
#pragma unroll
  for (int mi = 0; mi < 4; ++mi)
#pragma unroll
    for (int ni = 0; ni < 4; ++ni)
#pragma unroll
      for (int r = 0; r < 4; ++r) acc[mi][ni][r] = 0.f;

  for (int kt = 0; kt < Dm / 32; ++kt) {
    __syncthreads();
#pragma unroll
    for (int p = 0; p < 2; ++p) {
      gload16(Ags + (size_t)(m0 + p * 64 + rowt) * Dm + kt * 32 + cg8,
              &As[(p * 64 + w * 16) * 32]);
      gload16(Bts + (size_t)(n0 + p * 64 + rowt) * Dm + kt * 32 + cg8,
              &Bs[(p * 64 + w * 16) * 32]);
    }
    __syncthreads();
    short8 a[4], b[4];
#pragma unroll
    for (int mi = 0; mi < 4; ++mi)
      a[mi] = *reinterpret_cast<const short8*>(&As[(wr + mi * 16 + lr) * 32 + g * 8]);
#pragma unroll
    for (int ni = 0; ni < 4; ++ni)
      b[ni] = *reinterpret_cast<const short8*>(&Bs[(wc + ni * 16 + lr) * 32 + g * 8]);
#pragma unroll
    for (int mi = 0; mi < 4; ++mi)
#pragma unroll
      for (int ni = 0; ni < 4; ++ni)
        acc[mi][ni] = MFMA_BF16(a[mi], b[ni], acc[mi][ni], 0, 0, 0);
  }

#pragma unroll
  for (int mi = 0; mi < 4; ++mi)
#pragma unroll
    for (int ni = 0; ni < 4; ++ni)
#pragma unroll
      for (int r = 0; r < 4; ++r) {
        int mg = m0 + wr + mi * 16 + g * 4 + r;  // C/D: row=(lane>>4)*4+reg
        int ng = n0 + wc + ni * 16 + lr;         // C/D: col=lane&15
        float v = acc[mi][ni][r];
        int b_ = mg >> 11, t_ = mg & 2047, h_ = ng >> 6, d_ = ng & 63;
        size_t bh = (size_t)(b_ * NHm + h_);
        if (MODE == 0) {
          Cbf[(bh * Tm + t_) * HDm + d_] = (short)f2bf(v * kQScale);
        } else if (MODE == 1) {
          Cbf[((bh * NKT + (t_ >> 6)) << 12) + (t_ & 63) * 64 + (d_ ^ ((t_ & 7) << 3))] =
              (short)f2bf(v);
        } else if (MODE == 2) {
          Cbf[((bh * NKT + (t_ >> 6)) << 12) + d_ * 64 + ((t_ & 63) ^ ((d_ & 7) << 3))] =
              (short)f2bf(v);
        } else {
          Cf[(size_t)mg * Dm + ng] = v + bias[ng];
        }
      }
}

// Flash attention, causal, fixed-offset softmax (no running max: scores are
// bounded, exp2 can't overflow/underflow f32, and the scale cancels in O=PV/l).
// Block = (pair, bh): q-tiles pi and 15-pi -> every block = 34 stage-iters.
// l computed by MFMA with a ones B-fragment (same accum layout as o).
__global__ __launch_bounds__(256) void attn_kernel(
    const short* __restrict__ Qg, const short* __restrict__ Kg,
    const short* __restrict__ Vg, short* __restrict__ Og) {
  __shared__ __align__(16) short Kl[2][64 * 64];
  __shared__ __align__(16) short Vl[2][64 * 64];
  __shared__ __align__(16) short Pl[4][32 * 72];
  const int tid = threadIdx.x;
  const int lane = tid & 63;
  const int w = tid >> 6;
  const int g = lane >> 4;
  const int lr = lane & 15;
  const int bh = blockIdx.y;
  const int pi = blockIdx.x;
  const short* Ks = Kg + ((size_t)bh * NKT << 12);
  const short* Vs = Vg + ((size_t)bh * NKT << 12);
  short* Pw = &Pl[w][0];
  const int b_ = bh >> 4, h_ = bh & 15;

  short8 ones;
#pragma unroll
  for (int j = 0; j < 8; ++j) ones[j] = (short)0x3F80;  // bf16 1.0

  auto stage = [&](int t, int buf) {
#pragma unroll
    for (int i = 0; i < 2; ++i) {
      int ch = w * 2 + i;  // 8 chunks of 1024B per 8KB tile
      gload16(Ks + ((size_t)t << 12) + ch * 512 + lane * 8, &Kl[buf][ch * 512]);
      gload16(Vs + ((size_t)t << 12) + ch * 512 + lane * 8, &Vl[buf][ch * 512]);
    }
  };

  for (int pass = 0; pass < 2; ++pass) {
    const int qb = pass == 0 ? (15 - pi) : pi;  // heavy pass first
    const int q0 = qb * 128;
    const int qw = q0 + w * 32;
    const short* Qs = Qg + ((size_t)bh * Tm + q0) * HDm;

    short8 qf[2][2];
#pragma unroll
    for (int mi = 0; mi < 2; ++mi)
#pragma unroll
      for (int kk = 0; kk < 2; ++kk)
        qf[mi][kk] = *reinterpret_cast<const short8*>(
            Qs + (w * 32 + mi * 16 + lr) * HDm + kk * 32 + g * 8);

    f32x4 o[2][4], lacc[2];
#pragma unroll
    for (int mi = 0; mi < 2; ++mi)
#pragma unroll
      for (int r = 0; r < 4; ++r) {
        lacc[mi][r] = 0.f;
#pragma unroll
        for (int di = 0; di < 4; ++di) o[mi][di][r] = 0.f;
      }

    const int nt = q0 / 64 + 2;
    stage(0, 0);
    __syncthreads();  // buf0 ready (compiler drains vmcnt before barrier)
    int cur = 0;
    for (int t = 0; t < nt; ++t) {
      if (t + 1 < nt) stage(t + 1, cur ^ 1);  // next tile in flight over compute
      const int k0 = t * 64;
      const bool active = (k0 <= qw + 31);
      if (active) {
        // hoisted K fragments (swizzle is an involution on 8-short blocks)
        short8 kf[2][4];
#pragma unroll
        for (int ni = 0; ni < 4; ++ni) {
          int row = ni * 16 + lr;
#pragma unroll
          for (int kk = 0; kk < 2; ++kk)
            kf[kk][ni] = *reinterpret_cast<const short8*>(
                &Kl[cur][row * 64 + ((kk * 32 + g * 8) ^ ((row & 7) << 3))]);
        }
        f32x4 s[2][4];
#pragma unroll
        for (int mi = 0; mi < 2; ++mi)
#pragma unroll
          for (int ni = 0; ni < 4; ++ni) {
            f32x4 acc;
#pragma unroll
            for (int r = 0; r < 4; ++r) acc[r] = 0.f;
            acc = MFMA_BF16(qf[mi][0], kf[0][ni], acc, 0, 0, 0);
            acc = MFMA_BF16(qf[mi][1], kf[1][ni], acc, 0, 0, 0);
            s[mi][ni] = acc;
          }
        if (k0 + 63 > qw) {  // wave-uniform diag branch: apply causal mask
#pragma unroll
          for (int mi = 0; mi < 2; ++mi)
#pragma unroll
            for (int ni = 0; ni < 4; ++ni)
#pragma unroll
              for (int r = 0; r < 4; ++r)
                if (k0 + ni * 16 + lr > qw + mi * 16 + g * 4 + r) s[mi][ni][r] = -1e30f;
        }
        // p = exp2(s); P -> per-wave LDS (XOR-swizzled cols, conflict-free)
#pragma unroll
        for (int mi = 0; mi < 2; ++mi)
#pragma unroll
          for (int ni = 0; ni < 4; ++ni)
#pragma unroll
            for (int r = 0; r < 4; ++r)
              Pw[(mi * 16 + g * 4 + r) * 72 + ((ni * 16 + lr) ^ (g << 4))] =
                  (short)f2bf(fexp2(s[mi][ni][r]));

        // O += P @ V ; l += P @ 1  (V^T in LDS, swizzled cols)
#pragma unroll
        for (int kk = 0; kk < 2; ++kk) {
          short8 pf[2];
#pragma unroll
          for (int mi = 0; mi < 2; ++mi)
            pf[mi] = *reinterpret_cast<const short8*>(
                &Pw[(mi * 16 + lr) * 72 + ((kk * 32 + g * 8) ^ ((lr >> 2) << 4))]);
#pragma unroll
          for (int mi = 0; mi < 2; ++mi)
            lacc[mi] = MFMA_BF16(pf[mi], ones, lacc[mi], 0, 0, 0);
#pragma unroll
          for (int di = 0; di < 4; ++di) {
            int d = di * 16 + lr;
            short8 vf = *reinterpret_cast<const short8*>(
                &Vl[cur][d * 64 + ((kk * 32 + g * 8) ^ ((d & 7) << 3))]);
#pragma unroll
            for (int mi = 0; mi < 2; ++mi)
              o[mi][di] = MFMA_BF16(pf[mi], vf, o[mi][di], 0, 0, 0);
          }
        }
      }
      __syncthreads();  // drains stage(t+1); protects buf reuse + pass restart
      cur ^= 1;
    }

    // normalize, scatter to (B,T,D) bf16
#pragma unroll
    for (int mi = 0; mi < 2; ++mi)
#pragma unroll
      for (int di = 0; di < 4; ++di)
#pragma unroll
        for (int r = 0; r < 4; ++r) {
          float ov = o[mi][di][r] / lacc[mi][r];
          int qg = q0 + w * 32 + mi * 16 + g * 4 + r;
          int d_ = di * 16 + lr;
          Og[((size_t)b_ * Tm + qg) * Dm + h_ * HDm + d_] = (short)f2bf(ov);
        }
  }
}

extern "C" void kernel_launch(void* const* d_in, const int* in_sizes, int n_in,
                              void* d_out, int out_size, void* d_ws, size_t ws_size,
                              hipStream_t stream) {
  const float* X = (const float*)d_in[0];
  const float* Wq = (const float*)d_in[1];
  const float* Wk = (const float*)d_in[2];
  const float* Wv = (const float*)d_in[3];
  const float* Wo = (const float*)d_in[4];
  const float* bo = (const float*)d_in[5];
  float* out = (float*)d_out;

  char* ws = (char*)d_ws;
  short* Xb = (short*)ws;  ws += (size_t)Mtot * Dm * 2;
  short* Wqt = (short*)ws; ws += (size_t)Dm * Dm * 2;
  short* Wkt = (short*)ws; ws += (size_t)Dm * Dm * 2;
  short* Wvt = (short*)ws; ws += (size_t)Dm * Dm * 2;
  short* Wot = (short*)ws; ws += (size_t)Dm * Dm * 2;
  short* Qb = (short*)ws;  ws += (size_t)Mtot * Dm * 2;
  short* Kb = (short*)ws;  ws += (size_t)Mtot * Dm * 2;
  short* Vb = (short*)ws;  ws += (size_t)Mtot * Dm * 2;
  short* Ab = (short*)ws;  ws += (size_t)Mtot * Dm * 2;

  cvt_kernel<<<dim3(1024), dim3(256), 0, stream>>>(X, Xb, Mtot * Dm);
  cvt_t_kernel<<<dim3(16, 16, 4), dim3(256), 0, stream>>>(Wq, Wk, Wv, Wo, Wqt, Wkt, Wvt, Wot);

  dim3 ggrid(Dm / 128, Mtot / 128);  // (8, 64)
  gemm_bt_kernel<0><<<ggrid, 256, 0, stream>>>(Xb, Wqt, Qb, nullptr, nullptr);
  gemm_bt_kernel<1><<<ggrid, 256, 0, stream>>>(Xb, Wkt, Kb, nullptr, nullptr);
  gemm_bt_kernel<2><<<ggrid, 256, 0, stream>>>(Xb, Wvt, Vb, nullptr, nullptr);

  attn_kernel<<<dim3(8, Bb * NHm), 256, 0, stream>>>(Qb, Kb, Vb, Ab);

  gemm_bt_kernel<3><<<ggrid, 256, 0, stream>>>(Ab, Wot, nullptr, out, bo);
}

// Round 5
// 195.097 us; speedup vs baseline: 3.3912x; 1.0863x over previous
//
#include <hip/hip_runtime.h>
#include <hip/hip_bf16.h>
#include <math.h>

typedef __attribute__((ext_vector_type(8))) short short8;
typedef __attribute__((ext_vector_type(4))) float f32x4;

#define MFMA_BF16 __builtin_amdgcn_mfma_f32_16x16x32_bf16

static constexpr int Dm = 1024;
static constexpr int Tm = 2048;
static constexpr int Bb = 4;
static constexpr int NHm = 16;
static constexpr int HDm = 64;
static constexpr int Mtot = Bb * Tm;   // 8192
static constexpr int NKT = Tm / 64;    // 32 KV tiles per (b,h)
static constexpr float kQScale = 0.125f * 1.4426950408889634f;  // 1/sqrt(64) * log2(e)

__device__ __forceinline__ unsigned short f2bf(float f) {
  unsigned int u = __float_as_uint(f);
  u += 0x7FFFu + ((u >> 16) & 1u);  // RNE
  return (unsigned short)(u >> 16);
}

__device__ __forceinline__ float fexp2(float x) {  // raw v_exp_f32 (2^x)
  float r;
  asm("v_exp_f32 %0, %1" : "=v"(r) : "v"(x));
  return r;
}

__device__ __forceinline__ void gload16(const void* g, void* l) {
  __builtin_amdgcn_global_load_lds((const __attribute__((address_space(1))) void*)g,
                                   (__attribute__((address_space(3))) void*)l, 16, 0, 0);
}

__global__ __launch_bounds__(256) void cvt_kernel(const float* __restrict__ src,
                                                  short* __restrict__ dst, int n) {
  int stride = gridDim.x * blockDim.x;
  for (int i = blockIdx.x * blockDim.x + threadIdx.x; i * 4 < n; i += stride) {
    float4 v = reinterpret_cast<const float4*>(src)[i];
    short4 o;
    o.x = (short)f2bf(v.x);
    o.y = (short)f2bf(v.y);
    o.z = (short)f2bf(v.z);
    o.w = (short)f2bf(v.w);
    reinterpret_cast<short4*>(dst)[i] = o;
  }
}

// fused fp32->bf16 + transpose: Wt[n][k] = W[k][n], for all four weights
__global__ __launch_bounds__(256) void cvt_t_kernel(
    const float* __restrict__ W0, const float* __restrict__ W1,
    const float* __restrict__ W2, const float* __restrict__ W3,
    short* __restrict__ T0, short* __restrict__ T1,
    short* __restrict__ T2, short* __restrict__ T3) {
  const float* W = blockIdx.z == 0 ? W0 : blockIdx.z == 1 ? W1 : blockIdx.z == 2 ? W2 : W3;
  short* Wt = blockIdx.z == 0 ? T0 : blockIdx.z == 1 ? T1 : blockIdx.z == 2 ? T2 : T3;
  __shared__ __align__(16) short T[64 * 72];
  const int tid = threadIdx.x;
  const int k0 = blockIdx.y * 64, n0 = blockIdx.x * 64;
#pragma unroll
  for (int p = 0; p < 4; ++p) {
    int idx = tid + p * 256;
    int kr = idx >> 4, c4 = (idx & 15) * 4;
    float4 v = *reinterpret_cast<const float4*>(W + (size_t)(k0 + kr) * Dm + n0 + c4);
    T[(c4 + 0) * 72 + kr] = (short)f2bf(v.x);
    T[(c4 + 1) * 72 + kr] = (short)f2bf(v.y);
    T[(c4 + 2) * 72 + kr] = (short)f2bf(v.z);
    T[(c4 + 3) * 72 + kr] = (short)f2bf(v.w);
  }
  __syncthreads();
#pragma unroll
  for (int p = 0; p < 2; ++p) {
    int idx = tid + p * 256;
    int nr = idx >> 3, c8 = (idx & 7) * 8;
    *reinterpret_cast<short8*>(Wt + (size_t)(n0 + nr) * Dm + k0 + c8) =
        *reinterpret_cast<const short8*>(&T[nr * 72 + c8]);
  }
}

// Shared GEMM mainloop macro-structure (m97: 128x128, BK=32, global_load_lds).
// Fused QKV: z=0 -> Q (scaled, row-major bh layout), z=1 -> K LDS-image tiles,
// z=2 -> V^T LDS-image tiles.
__global__ __launch_bounds__(256) void gemm_qkv_kernel(
    const short* __restrict__ Ags, const short* __restrict__ Wq,
    const short* __restrict__ Wk, const short* __restrict__ Wv,
    short* __restrict__ Qo, short* __restrict__ Ko, short* __restrict__ Vo) {
  __shared__ __align__(16) short As[128 * 32];
  __shared__ __align__(16) short Bs[128 * 32];
  const int z = blockIdx.z;
  const short* Bts = z == 0 ? Wq : z == 1 ? Wk : Wv;
  short* Co = z == 0 ? Qo : z == 1 ? Ko : Vo;
  const int tid = threadIdx.x;
  const int lane = tid & 63;
  const int w = tid >> 6;
  const int wr = (w >> 1) * 64, wc = (w & 1) * 64;
  const int g = lane >> 4;
  const int lr = lane & 15;
  const int m0 = blockIdx.y * 128;
  const int n0 = blockIdx.x * 128;
  const int rowt = tid >> 2;
  const int cg8 = (tid & 3) * 8;

  f32x4 acc[4][4];
#pragma unroll
  for (int mi = 0; mi < 4; ++mi)
#pragma unroll
    for (int ni = 0; ni < 4; ++ni)
#pragma unroll
      for (int r = 0; r < 4; ++r) acc[mi][ni][r] = 0.f;

  for (int kt = 0; kt < Dm / 32; ++kt) {
    __syncthreads();
#pragma unroll
    for (int p = 0; p < 2; ++p) {
      gload16(Ags + (size_t)(m0 + p * 64 + rowt) * Dm + kt * 32 + cg8,
              &As[(p * 64 + w * 16) * 32]);
      gload16(Bts + (size_t)(n0 + p * 64 + rowt) * Dm + kt * 32 + cg8,
              &Bs[(p * 64 + w * 16) * 32]);
    }
    __syncthreads();
    short8 a[4], b[4];
#pragma unroll
    for (int mi = 0; mi < 4; ++mi)
      a[mi] = *reinterpret_cast<const short8*>(&As[(wr + mi * 16 + lr) * 32 + g * 8]);
#pragma unroll
    for (int ni = 0; ni < 4; ++ni)
      b[ni] = *reinterpret_cast<const short8*>(&Bs[(wc + ni * 16 + lr) * 32 + g * 8]);
#pragma unroll
    for (int mi = 0; mi < 4; ++mi)
#pragma unroll
      for (int ni = 0; ni < 4; ++ni)
        acc[mi][ni] = MFMA_BF16(a[mi], b[ni], acc[mi][ni], 0, 0, 0);
  }

#pragma unroll
  for (int mi = 0; mi < 4; ++mi)
#pragma unroll
    for (int ni = 0; ni < 4; ++ni)
#pragma unroll
      for (int r = 0; r < 4; ++r) {
        int mg = m0 + wr + mi * 16 + g * 4 + r;  // C/D: row=(lane>>4)*4+reg
        int ng = n0 + wc + ni * 16 + lr;         // C/D: col=lane&15
        float v = acc[mi][ni][r];
        int b_ = mg >> 11, t_ = mg & 2047, h_ = ng >> 6, d_ = ng & 63;
        size_t bh = (size_t)(b_ * NHm + h_);
        if (z == 0) {
          Co[(bh * Tm + t_) * HDm + d_] = (short)f2bf(v * kQScale);
        } else if (z == 1) {
          Co[((bh * NKT + (t_ >> 6)) << 12) + (t_ & 63) * 64 + (d_ ^ ((t_ & 7) << 3))] =
              (short)f2bf(v);
        } else {
          Co[((bh * NKT + (t_ >> 6)) << 12) + d_ * 64 + ((t_ & 63) ^ ((d_ & 7) << 3))] =
              (short)f2bf(v);
        }
      }
}

// Out-projection: fp32 + bias, row-major
__global__ __launch_bounds__(256) void gemm_out_kernel(
    const short* __restrict__ Ags, const short* __restrict__ Bts,
    float* __restrict__ Cf, const float* __restrict__ bias) {
  __shared__ __align__(16) short As[128 * 32];
  __shared__ __align__(16) short Bs[128 * 32];
  const int tid = threadIdx.x;
  const int lane = tid & 63;
  const int w = tid >> 6;
  const int wr = (w >> 1) * 64, wc = (w & 1) * 64;
  const int g = lane >> 4;
  const int lr = lane & 15;
  const int m0 = blockIdx.y * 128;
  const int n0 = blockIdx.x * 128;
  const int rowt = tid >> 2;
  const int cg8 = (tid & 3) * 8;

  f32x4 acc[4][4];
#pragma unroll
  for (int mi = 0; mi < 4; ++mi)
#pragma unroll
    for (int ni = 0; ni < 4; ++ni)
#pragma unroll
      for (int r = 0; r < 4; ++r) acc[mi][ni][r] = 0.f;

  for (int kt = 0; kt < Dm / 32; ++kt) {
    __syncthreads();
#pragma unroll
    for (int p = 0; p < 2; ++p) {
      gload16(Ags + (size_t)(m0 + p * 64 + rowt) * Dm + kt * 32 + cg8,
              &As[(p * 64 + w * 16) * 32]);
      gload16(Bts + (size_t)(n0 + p * 64 + rowt) * Dm + kt * 32 + cg8,
              &Bs[(p * 64 + w * 16) * 32]);
    }
    __syncthreads();
    short8 a[4], b[4];
#pragma unroll
    for (int mi = 0; mi < 4; ++mi)
      a[mi] = *reinterpret_cast<const short8*>(&As[(wr + mi * 16 + lr) * 32 + g * 8]);
#pragma unroll
    for (int ni = 0; ni < 4; ++ni)
      b[ni] = *reinterpret_cast<const short8*>(&Bs[(wc + ni * 16 + lr) * 32 + g * 8]);
#pragma unroll
    for (int mi = 0; mi < 4; ++mi)
#pragma unroll
      for (int ni = 0; ni < 4; ++ni)
        acc[mi][ni] = MFMA_BF16(a[mi], b[ni], acc[mi][ni], 0, 0, 0);
  }

#pragma unroll
  for (int mi = 0; mi < 4; ++mi)
#pragma unroll
    for (int ni = 0; ni < 4; ++ni)
#pragma unroll
      for (int r = 0; r < 4; ++r) {
        int mg = m0 + wr + mi * 16 + g * 4 + r;
        int ng = n0 + wc + ni * 16 + lr;
        Cf[(size_t)mg * Dm + ng] = acc[mi][ni][r] + bias[ng];
      }
}

// Flash attention, causal, fixed-offset softmax (scores bounded; exp2 safe in
// f32; scale cancels in O=PV/l). Block=(bh, pair): q-tiles pi and 15-pi.
// grid.x = bh so the 8 pair-blocks of one bh share id%8 -> same XCD L2.
// 3-buffer, 2-deep prefetch with counted vmcnt (never 0 mid-loop).
__global__ __launch_bounds__(256) void attn_kernel(
    const short* __restrict__ Qg, const short* __restrict__ Kg,
    const short* __restrict__ Vg, short* __restrict__ Og) {
  __shared__ __align__(16) short Kl[3][64 * 64];
  __shared__ __align__(16) short Vl[3][64 * 64];
  __shared__ __align__(16) short Pl[4][32 * 72];
  const int tid = threadIdx.x;
  const int lane = tid & 63;
  const int w = tid >> 6;
  const int g = lane >> 4;
  const int lr = lane & 15;
  const int bh = blockIdx.x;   // XCD locality: same-bh blocks -> same id%8
  const int pi = blockIdx.y;
  const short* Ks = Kg + ((size_t)bh * NKT << 12);
  const short* Vs = Vg + ((size_t)bh * NKT << 12);
  short* Pw = &Pl[w][0];
  const int b_ = bh >> 4, h_ = bh & 15;

  short8 ones;
#pragma unroll
  for (int j = 0; j < 8; ++j) ones[j] = (short)0x3F80;  // bf16 1.0

  auto stage = [&](int t, int buf) {
#pragma unroll
    for (int i = 0; i < 2; ++i) {
      int ch = w * 2 + i;  // 8 chunks of 1024B per 8KB tile; 4 loads/wave total
      gload16(Ks + ((size_t)t << 12) + ch * 512 + lane * 8, &Kl[buf][ch * 512]);
      gload16(Vs + ((size_t)t << 12) + ch * 512 + lane * 8, &Vl[buf][ch * 512]);
    }
  };

  for (int pass = 0; pass < 2; ++pass) {
    const int qb = pass == 0 ? (15 - pi) : pi;  // heavy pass first
    const int q0 = qb * 128;
    const int qw = q0 + w * 32;
    const short* Qs = Qg + ((size_t)bh * Tm + q0) * HDm;

    short8 qf[2][2];
#pragma unroll
    for (int mi = 0; mi < 2; ++mi)
#pragma unroll
      for (int kk = 0; kk < 2; ++kk)
        qf[mi][kk] = *reinterpret_cast<const short8*>(
            Qs + (w * 32 + mi * 16 + lr) * HDm + kk * 32 + g * 8);

    f32x4 o[2][4], lacc[2];
#pragma unroll
    for (int mi = 0; mi < 2; ++mi)
#pragma unroll
      for (int r = 0; r < 4; ++r) {
        lacc[mi][r] = 0.f;
#pragma unroll
        for (int di = 0; di < 4; ++di) o[mi][di][r] = 0.f;
      }

    const int nt = q0 / 64 + 2;
    stage(0, 0);
    stage(1, 1);
    for (int t = 0; t < nt; ++t) {
      // wait for tile t only; tile t+1's 4 loads stay in flight across barrier
      if (t < nt - 1) asm volatile("s_waitcnt vmcnt(4)" ::: "memory");
      else            asm volatile("s_waitcnt vmcnt(0)" ::: "memory");
      __builtin_amdgcn_s_barrier();
      __builtin_amdgcn_sched_barrier(0);
      if (t + 2 < nt) stage(t + 2, (t + 2) % 3);  // 2 compute phases to land
      const int cur = t % 3;
      const int k0 = t * 64;
      const bool active = (k0 <= qw + 31);
      if (active) {
        // hoisted K fragments (swizzle is an involution on 8-short blocks)
        short8 kf[2][4];
#pragma unroll
        for (int ni = 0; ni < 4; ++ni) {
          int row = ni * 16 + lr;
#pragma unroll
          for (int kk = 0; kk < 2; ++kk)
            kf[kk][ni] = *reinterpret_cast<const short8*>(
                &Kl[cur][row * 64 + ((kk * 32 + g * 8) ^ ((row & 7) << 3))]);
        }
        f32x4 s[2][4];
#pragma unroll
        for (int mi = 0; mi < 2; ++mi)
#pragma unroll
          for (int ni = 0; ni < 4; ++ni) {
            f32x4 acc;
#pragma unroll
            for (int r = 0; r < 4; ++r) acc[r] = 0.f;
            acc = MFMA_BF16(qf[mi][0], kf[0][ni], acc, 0, 0, 0);
            acc = MFMA_BF16(qf[mi][1], kf[1][ni], acc, 0, 0, 0);
            s[mi][ni] = acc;
          }
        if (k0 + 63 > qw) {  // wave-uniform diag branch: apply causal mask
#pragma unroll
          for (int mi = 0; mi < 2; ++mi)
#pragma unroll
            for (int ni = 0; ni < 4; ++ni)
#pragma unroll
              for (int r = 0; r < 4; ++r)
                if (k0 + ni * 16 + lr > qw + mi * 16 + g * 4 + r) s[mi][ni][r] = -1e30f;
        }
        // p = exp2(s); P -> per-wave LDS (XOR-swizzled cols, conflict-free)
#pragma unroll
        for (int mi = 0; mi < 2; ++mi)
#pragma unroll
          for (int ni = 0; ni < 4; ++ni)
#pragma unroll
            for (int r = 0; r < 4; ++r)
              Pw[(mi * 16 + g * 4 + r) * 72 + ((ni * 16 + lr) ^ (g << 4))] =
                  (short)f2bf(fexp2(s[mi][ni][r]));

        // O += P @ V ; l += P @ 1  (V^T in LDS, swizzled cols)
#pragma unroll
        for (int kk = 0; kk < 2; ++kk) {
          short8 pf[2];
#pragma unroll
          for (int mi = 0; mi < 2; ++mi)
            pf[mi] = *reinterpret_cast<const short8*>(
                &Pw[(mi * 16 + lr) * 72 + ((kk * 32 + g * 8) ^ ((lr >> 2) << 4))]);
#pragma unroll
          for (int mi = 0; mi < 2; ++mi)
            lacc[mi] = MFMA_BF16(pf[mi], ones, lacc[mi], 0, 0, 0);
#pragma unroll
          for (int di = 0; di < 4; ++di) {
            int d = di * 16 + lr;
            short8 vf = *reinterpret_cast<const short8*>(
                &Vl[cur][d * 64 + ((kk * 32 + g * 8) ^ ((d & 7) << 3))]);
#pragma unroll
            for (int mi = 0; mi < 2; ++mi)
              o[mi][di] = MFMA_BF16(pf[mi], vf, o[mi][di], 0, 0, 0);
          }
        }
      }
    }
    __syncthreads();  // pass boundary: all reads done before buffers restaged

    // normalize, scatter to (B,T,D) bf16
#pragma unroll
    for (int mi = 0; mi < 2; ++mi)
#pragma unroll
      for (int di = 0; di < 4; ++di)
#pragma unroll
        for (int r = 0; r < 4; ++r) {
          float ov = o[mi][di][r] / lacc[mi][r];
          int qg = q0 + w * 32 + mi * 16 + g * 4 + r;
          int d_ = di * 16 + lr;
          Og[((size_t)b_ * Tm + qg) * Dm + h_ * HDm + d_] = (short)f2bf(ov);
        }
  }
}

extern "C" void kernel_launch(void* const* d_in, const int* in_sizes, int n_in,
                              void* d_out, int out_size, void* d_ws, size_t ws_size,
                              hipStream_t stream) {
  const float* X = (const float*)d_in[0];
  const float* Wq = (const float*)d_in[1];
  const float* Wk = (const float*)d_in[2];
  const float* Wv = (const float*)d_in[3];
  const float* Wo = (const float*)d_in[4];
  const float* bo = (const float*)d_in[5];
  float* out = (float*)d_out;

  char* ws = (char*)d_ws;
  short* Xb = (short*)ws;  ws += (size_t)Mtot * Dm * 2;
  short* Wqt = (short*)ws; ws += (size_t)Dm * Dm * 2;
  short* Wkt = (short*)ws; ws += (size_t)Dm * Dm * 2;
  short* Wvt = (short*)ws; ws += (size_t)Dm * Dm * 2;
  short* Wot = (short*)ws; ws += (size_t)Dm * Dm * 2;
  short* Qb = (short*)ws;  ws += (size_t)Mtot * Dm * 2;
  short* Kb = (short*)ws;  ws += (size_t)Mtot * Dm * 2;
  short* Vb = (short*)ws;  ws += (size_t)Mtot * Dm * 2;
  short* Ab = (short*)ws;  ws += (size_t)Mtot * Dm * 2;

  cvt_kernel<<<dim3(1024), dim3(256), 0, stream>>>(X, Xb, Mtot * Dm);
  cvt_t_kernel<<<dim3(16, 16, 4), dim3(256), 0, stream>>>(Wq, Wk, Wv, Wo, Wqt, Wkt, Wvt, Wot);

  gemm_qkv_kernel<<<dim3(Dm / 128, Mtot / 128, 3), 256, 0, stream>>>(
      Xb, Wqt, Wkt, Wvt, Qb, Kb, Vb);

  attn_kernel<<<dim3(Bb * NHm, 8), 256, 0, stream>>>(Qb, Kb, Vb, Ab);

  gemm_out_kernel<<<dim3(Dm / 128, Mtot / 128), 256, 0, stream>>>(Ab, Wot, out, bo);
}